// Round 1
// baseline (164.935 us; speedup 1.0000x reference)
//
#include <hip/hip_runtime.h>
#include <math.h>

#define BATCH 64
#define NPG 9
#define N_NODES 576
#define HD 128
#define SPEC_LEN 1801
#define S1DIM 900
#define SCOMP 100
#define ASL 243
#define KC 16
#define KLEN 113   // 16*113 = 1808 >= 1801; last chunk = 106

// ---------- Kernel 0: transpose specs [64][1801] -> sT [1801][64] ----------
__global__ __launch_bounds__(256) void k_transpose(const float* __restrict__ specs,
                                                   float* __restrict__ sT) {
    int idx = blockIdx.x * 256 + threadIdx.x;
    if (idx < SPEC_LEN * 64) {
        int k = idx >> 6, m = idx & 63;
        sT[idx] = specs[m * SPEC_LEN + k];
    }
}

// ---------- Kernel 1: GEMM1 partials: P[kc][m][n] = sum_{k in chunk} specs[m][k]*W1[k][n]
// one wave per block; lanes = n; m0 uniform -> specs via scalar loads from sT
__global__ __launch_bounds__(64) void k_gemm1(const float* __restrict__ sT,
                                              const float* __restrict__ W1,
                                              float* __restrict__ P) {
    int nt = blockIdx.x;        // 0..14
    int mg = blockIdx.y;        // 0..3
    int kc = blockIdx.z;        // 0..15
    int lane = threadIdx.x;
    int n = nt * 64 + lane;
    bool valid = n < S1DIM;
    int m0 = mg * 16;
    int kbase = kc * KLEN;
    int klen = min(KLEN, SPEC_LEN - kbase);

    float acc[16];
#pragma unroll
    for (int i = 0; i < 16; ++i) acc[i] = 0.0f;

    const float* __restrict__ spB = sT + kbase * 64 + m0;  // uniform base
    const float* __restrict__ w1p = W1 + kbase * S1DIM + n;

    for (int kl = 0; kl < klen; ++kl) {
        float w = valid ? w1p[kl * S1DIM] : 0.0f;
        const float* __restrict__ sp = spB + kl * 64;   // fully uniform address
#pragma unroll
        for (int i = 0; i < 16; ++i)
            acc[i] = fmaf(sp[i], w, acc[i]);
    }
    if (valid) {
#pragma unroll
        for (int i = 0; i < 16; ++i)
            P[(kc * 64 + m0 + i) * S1DIM + n] = acc[i];
    }
}

// ---------- Kernel 2: fused  (blocks 0..63: reduce+bias+relu -> GEMM2 -> D -> value head)
//                             (blocks 64..207: AB = relu(nf) @ Wa2[0:256])
__global__ __launch_bounds__(256) void k_mid(const float* __restrict__ P,
                                             const float* __restrict__ b1,
                                             const float* __restrict__ W2,
                                             const float* __restrict__ b2,
                                             const float* __restrict__ Wa2,
                                             const float* __restrict__ nf,
                                             const float* __restrict__ Wv1,
                                             const float* __restrict__ bv1,
                                             const float* __restrict__ Wv2,
                                             const float* __restrict__ bv2,
                                             float* __restrict__ Dout,
                                             float* __restrict__ AB,
                                             float* __restrict__ vout) {
    int tid = threadIdx.x;
    if (blockIdx.x >= BATCH) {
        // ---- AB path: 4 node-rows per block ----
        __shared__ __align__(16) float snf[4 * HD];
        int i0 = (blockIdx.x - BATCH) * 4;
        for (int idx = tid; idx < 4 * HD; idx += 256)
            snf[idx] = fmaxf(nf[i0 * HD + idx], 0.0f);
        __syncthreads();
        int c = tid;  // 0..255 : c<128 -> Ai col c ; else Bj col c-128
        const float* __restrict__ wp = (c < HD) ? (Wa2 + c) : (Wa2 + HD * HD + (c - HD));
        float a0 = 0.f, a1 = 0.f, a2 = 0.f, a3 = 0.f;
        for (int k = 0; k < HD; ++k) {
            float w = wp[k * HD];
            a0 = fmaf(snf[k], w, a0);
            a1 = fmaf(snf[HD + k], w, a1);
            a2 = fmaf(snf[2 * HD + k], w, a2);
            a3 = fmaf(snf[3 * HD + k], w, a3);
        }
        AB[(i0 + 0) * 256 + c] = a0;
        AB[(i0 + 1) * 256 + c] = a1;
        AB[(i0 + 2) * 256 + c] = a2;
        AB[(i0 + 3) * 256 + c] = a3;
        return;
    }
    // ---- graph path ----
    int m = blockIdx.x;
    __shared__ __align__(16) float s1row[S1DIM];
    __shared__ __align__(16) float srow[SCOMP];
    __shared__ __align__(16) float ro[HD];

    // A: reduce partials + bias + relu
    for (int n = tid; n < S1DIM; n += 256) {
        float a = b1[n];
#pragma unroll
        for (int kc = 0; kc < KC; ++kc)
            a += P[(kc * 64 + m) * S1DIM + n];
        s1row[n] = fmaxf(a, 0.0f);
    }
    __syncthreads();
    // B: s = relu(s1 @ W2 + b2)
    if (tid < SCOMP) {
        float a = b2[tid];
        for (int k = 0; k < S1DIM; k += 4) {
            const float4 f = *(const float4*)&s1row[k];
            a = fmaf(f.x, W2[(k + 0) * SCOMP + tid], a);
            a = fmaf(f.y, W2[(k + 1) * SCOMP + tid], a);
            a = fmaf(f.z, W2[(k + 2) * SCOMP + tid], a);
            a = fmaf(f.w, W2[(k + 3) * SCOMP + tid], a);
        }
        srow[tid] = fmaxf(a, 0.0f);
    }
    __syncthreads();
    // C: D = s @ Wa2[256:]   (tid<128)  |  readout (tid>=128)
    if (tid < HD) {
        float a = 0.0f;
        for (int k = 0; k < SCOMP; ++k)
            a = fmaf(srow[k], Wa2[(2 * HD + k) * HD + tid], a);
        Dout[m * HD + tid] = a;
    } else if (tid < HD + 128) {
        int h = tid - HD;
        float a = 0.0f;
#pragma unroll
        for (int i = 0; i < NPG; ++i) a += nf[(m * NPG + i) * HD + h];
        ro[h] = a;
    }
    __syncthreads();
    // D: value head (wave 0)
    if (tid < 64) {
        float a = bv1[tid];
        for (int k = 0; k < HD; ++k) a = fmaf(ro[k], Wv1[k * 64 + tid], a);
        for (int k = 0; k < SCOMP; ++k) a = fmaf(srow[k], Wv1[(HD + k) * 64 + tid], a);
        a = fmaxf(a, 0.0f);
        float p = a * Wv2[tid];
#pragma unroll
        for (int off = 32; off; off >>= 1) p += __shfl_down(p, off, 64);
        if (tid == 0) vout[m] = p + bv2[0];
    }
}

// ---------- Kernel 3: per-graph pair head + gather + softmax ----------
__global__ __launch_bounds__(256) void k_final(const float* __restrict__ AB,
                                               const float* __restrict__ Dv,
                                               const float* __restrict__ ba2,
                                               const float* __restrict__ Wf,
                                               const float* __restrict__ bfb,
                                               const int* __restrict__ indexmask,
                                               const float* __restrict__ mask,
                                               float* __restrict__ out) {
    int b = blockIdx.x, tid = threadIdx.x;
    __shared__ float sAi[NPG * 132];
    __shared__ float sBj[NPG * 132];
    __shared__ float sC[HD];
    __shared__ float sWf[HD * 3];
    __shared__ float fp[ASL];
    __shared__ float red[8];

    for (int idx = tid; idx < NPG * 256; idx += 256) {
        int i = idx >> 8, c = idx & 255;
        float v = AB[(b * NPG + i) * 256 + c];
        if (c < HD) sAi[i * 132 + c] = v;
        else        sBj[i * 132 + (c - HD)] = v;
    }
    if (tid < HD) sC[tid] = Dv[b * HD + tid] + ba2[tid];
    for (int idx = tid; idx < HD * 3; idx += 256) sWf[idx] = Wf[idx];
    __syncthreads();

    if (tid < ASL) {
        int i = tid / 27;
        int j = (tid / 3) % 9;
        int bo = tid % 3;
        float a = bfb[bo];
        const float* pa = sAi + i * 132;
        const float* pb = sBj + j * 132;
        for (int h = 0; h < HD; ++h) {
            float t = fmaxf(pa[h] + pb[h] + sC[h], 0.0f);
            a = fmaf(t, sWf[h * 3 + bo], a);
        }
        fp[tid] = a;
    }
    __syncthreads();

    float g = -INFINITY;
    if (tid < ASL) g = fp[indexmask[b * ASL + tid]] + mask[b * ASL + tid];
    float mx = g;
#pragma unroll
    for (int off = 32; off; off >>= 1) mx = fmaxf(mx, __shfl_down(mx, off, 64));
    if ((tid & 63) == 0) red[tid >> 6] = mx;
    __syncthreads();
    mx = fmaxf(fmaxf(red[0], red[1]), fmaxf(red[2], red[3]));
    float e = (tid < ASL) ? __expf(g - mx) : 0.0f;
    float sm = e;
#pragma unroll
    for (int off = 32; off; off >>= 1) sm += __shfl_down(sm, off, 64);
    if ((tid & 63) == 0) red[4 + (tid >> 6)] = sm;
    __syncthreads();
    sm = red[4] + red[5] + red[6] + red[7];
    if (tid < ASL) out[b * ASL + tid] = e / sm;
}

extern "C" void kernel_launch(void* const* d_in, const int* in_sizes, int n_in,
                              void* d_out, int out_size, void* d_ws, size_t ws_size,
                              hipStream_t stream) {
    (void)in_sizes; (void)n_in; (void)out_size; (void)ws_size;
    const float* nf    = (const float*)d_in[0];
    const float* specs = (const float*)d_in[1];
    /* d_in[2] len_vec: structure known (contiguous 9-node blocks) */
    const float* mask  = (const float*)d_in[3];
    const int*   idxm  = (const int*)d_in[4];
    const float* W1  = (const float*)d_in[5];
    const float* b1  = (const float*)d_in[6];
    const float* W2  = (const float*)d_in[7];
    const float* b2  = (const float*)d_in[8];
    const float* Wv1 = (const float*)d_in[9];
    const float* bv1 = (const float*)d_in[10];
    const float* Wv2 = (const float*)d_in[11];
    const float* bv2 = (const float*)d_in[12];
    const float* Wa2 = (const float*)d_in[13];
    const float* ba2 = (const float*)d_in[14];
    const float* Wf  = (const float*)d_in[15];
    const float* bfv = (const float*)d_in[16];
    float* out = (float*)d_out;
    float* ws  = (float*)d_ws;

    float* sT = ws;                          // 1801*64   = 115264
    float* P  = sT + SPEC_LEN * 64;          // 16*64*900 = 921600
    float* Dv = P + KC * 64 * S1DIM;         // 64*128    = 8192
    float* AB = Dv + BATCH * HD;             // 576*256   = 147456

    k_transpose<<<dim3(451), dim3(256), 0, stream>>>(specs, sT);
    k_gemm1<<<dim3(15, 4, KC), dim3(64), 0, stream>>>(sT, W1, P);
    k_mid<<<dim3(BATCH + N_NODES / 4), dim3(256), 0, stream>>>(P, b1, W2, b2, Wa2, nf,
                                                               Wv1, bv1, Wv2, bv2,
                                                               Dv, AB, out + BATCH * ASL);
    k_final<<<dim3(BATCH), dim3(256), 0, stream>>>(AB, Dv, ba2, Wf, bfv, idxm, mask, out);
}

// Round 2
// 148.175 us; speedup vs baseline: 1.1131x; 1.1131x over previous
//
#include <hip/hip_runtime.h>
#include <math.h>

#define BATCH 64
#define NPG 9
#define N_NODES 576
#define HD 128
#define SPEC_LEN 1801
#define S1DIM 900
#define SCOMP 100
#define ASL 243
#define NT 15          // n-tiles of 64 over 900
#define KC 17          // K chunks
#define KCH 106        // ceil(1801/17); 17*106 = 1802
#define KT 1856        // padded sT rows (29*64)

// ---------- Kernel 0: transpose specs -> sT[1856][64] (zero-padded) + zero s1pre ----------
__global__ __launch_bounds__(256) void k_prep(const float* __restrict__ specs,
                                              float* __restrict__ sT,
                                              float* __restrict__ s1pre) {
    int bb = blockIdx.x, tid = threadIdx.x;
    if (bb < 29) {
        __shared__ float t[64 * 65];
        int k0 = bb * 64;
        int kk = tid & 63, mq = tid >> 6;
#pragma unroll
        for (int p = 0; p < 16; ++p) {
            int m = p * 4 + mq;
            int k = k0 + kk;
            float v = (k < SPEC_LEN) ? specs[(size_t)m * SPEC_LEN + k] : 0.0f;
            t[kk * 65 + m] = v;
        }
        __syncthreads();
#pragma unroll
        for (int p = 0; p < 16; ++p) {
            int o = p * 256 + tid;
            sT[(size_t)k0 * 64 + o] = t[(o >> 6) * 65 + (o & 63)];
        }
    } else {
        int idx = (bb - 29) * 1024 + tid * 4;
        if (idx < BATCH * S1DIM)
            *(float4*)(s1pre + idx) = make_float4(0.f, 0.f, 0.f, 0.f);
    }
}

// ---------- Kernel 1: GEMM1 (atomic K-split) + AB = relu(nf) @ Wa2[0:256] ----------
__global__ __launch_bounds__(256) void k_main(const float* __restrict__ sT,
                                              const float* __restrict__ W1,
                                              const float* __restrict__ nf,
                                              const float* __restrict__ Wa2,
                                              float* __restrict__ s1pre,
                                              float* __restrict__ AB) {
    int bb = blockIdx.x, tid = threadIdx.x;
    if (bb < NT * KC) {
        // ---- GEMM1 path: tile = 64 m x 64 n x 106 k ----
        __shared__ float w1t[16][64];
        int nt = bb % NT, kc = bb / NT;
        int n0 = nt * 64;
        int lane = tid & 63;
        int wid = __builtin_amdgcn_readfirstlane(tid >> 6);
        int m0 = wid * 16;                       // wave-uniform
        int n = n0 + lane;
        int kb = kc * KCH;
        int klen = min(KCH, SPEC_LEN - kb);      // 106 (105 for last chunk)
        bool nv = (n < S1DIM);

        float acc[16];
#pragma unroll
        for (int i = 0; i < 16; ++i) acc[i] = 0.0f;

        for (int s = 0; s < 7; ++s) {            // 7*16 = 112 >= 106
#pragma unroll
            for (int p = 0; p < 4; ++p) {
                int e = tid + p * 256;
                int kl = s * 16 + (e >> 6);
                int nn = e & 63;
                float v = 0.0f;
                if (kl < klen && (n0 + nn) < S1DIM)
                    v = W1[(size_t)(kb + kl) * S1DIM + n0 + nn];
                w1t[e >> 6][nn] = v;
            }
            __syncthreads();
            const float* sa_base = sT + (size_t)(kb + s * 16) * 64 + m0;  // uniform
#pragma unroll
            for (int kk = 0; kk < 16; ++kk) {
                float w = w1t[kk][lane];
                const float* sa = sa_base + kk * 64;  // wave-uniform -> s_load
#pragma unroll
                for (int i = 0; i < 16; ++i)
                    acc[i] = fmaf(sa[i], w, acc[i]);
            }
            __syncthreads();
        }
        if (nv) {
#pragma unroll
            for (int i = 0; i < 16; ++i)
                atomicAdd(&s1pre[(size_t)(m0 + i) * S1DIM + n], acc[i]);
        }
    } else {
        // ---- AB path: 2 node-rows per block ----
        __shared__ float snf[256];
        int ib = (bb - NT * KC) * 2;
        snf[tid] = fmaxf(nf[(size_t)ib * HD + tid], 0.0f);
        __syncthreads();
        int c = tid;
        const float* __restrict__ wp = (c < HD) ? (Wa2 + c) : (Wa2 + HD * HD + (c - HD));
        float a0 = 0.f, a1 = 0.f;
#pragma unroll 8
        for (int k = 0; k < HD; ++k) {
            float w = wp[(size_t)k * HD];
            a0 = fmaf(snf[k], w, a0);
            a1 = fmaf(snf[HD + k], w, a1);
        }
        AB[(size_t)ib * 256 + c] = a0;
        AB[(size_t)(ib + 1) * 256 + c] = a1;
    }
}

// ---------- Kernel 2: per-graph everything else ----------
__global__ __launch_bounds__(256) void k_head(const float* __restrict__ s1pre,
                                              const float* __restrict__ b1,
                                              const float* __restrict__ W2,
                                              const float* __restrict__ b2,
                                              const float* __restrict__ Wa2,
                                              const float* __restrict__ nf,
                                              const float* __restrict__ Wv1,
                                              const float* __restrict__ bv1,
                                              const float* __restrict__ Wv2,
                                              const float* __restrict__ bv2,
                                              const float* __restrict__ ba2,
                                              const float* __restrict__ Wf,
                                              const float* __restrict__ bfb,
                                              const int* __restrict__ indexmask,
                                              const float* __restrict__ mask,
                                              const float* __restrict__ AB,
                                              float* __restrict__ out,
                                              float* __restrict__ vout) {
    int m = blockIdx.x, tid = threadIdx.x;
    __shared__ __align__(16) float s1row[S1DIM];
    __shared__ __align__(16) float sAi[NPG * 132];
    __shared__ __align__(16) float sBj[NPG * 132];
    __shared__ __align__(16) float sWfT[3 * HD];
    __shared__ __align__(16) float srow[SCOMP];
    __shared__ __align__(16) float ro[HD];
    __shared__ __align__(16) float sC[HD];
    __shared__ float fp[ASL];
    __shared__ float red[8];

    // (a) staging
    for (int e = tid; e < S1DIM; e += 256)
        s1row[e] = fmaxf(s1pre[(size_t)m * S1DIM + e] + b1[e], 0.0f);
    for (int e = tid; e < NPG * 256; e += 256) {
        int i = e >> 8, c = e & 255;
        float v = AB[(size_t)(m * NPG + i) * 256 + c];
        if (c < HD) sAi[i * 132 + c] = v;
        else        sBj[i * 132 + (c - HD)] = v;
    }
    for (int e = tid; e < 3 * HD; e += 256)
        sWfT[(e % 3) * HD + (e / 3)] = Wf[e];
    if (tid >= 128) {
        int h = tid - 128;
        float a = 0.0f;
#pragma unroll
        for (int i = 0; i < NPG; ++i) a += nf[(size_t)(m * NPG + i) * HD + h];
        ro[h] = a;
    }
    __syncthreads();

    // (b) GEMM2: s = relu(s1 @ W2 + b2)
    if (tid < SCOMP) {
        float a = b2[tid];
        for (int k = 0; k < S1DIM; k += 4) {
            const float4 f = *(const float4*)&s1row[k];
            a = fmaf(f.x, W2[(size_t)(k + 0) * SCOMP + tid], a);
            a = fmaf(f.y, W2[(size_t)(k + 1) * SCOMP + tid], a);
            a = fmaf(f.z, W2[(size_t)(k + 2) * SCOMP + tid], a);
            a = fmaf(f.w, W2[(size_t)(k + 3) * SCOMP + tid], a);
        }
        srow[tid] = fmaxf(a, 0.0f);
    }
    __syncthreads();

    // (c) D + ba2 -> sC (tid<128)  |  value head (tid 128..191)
    if (tid < HD) {
        float a = 0.0f;
        for (int k = 0; k < SCOMP; ++k)
            a = fmaf(srow[k], Wa2[(size_t)(2 * HD + k) * HD + tid], a);
        sC[tid] = a + ba2[tid];
    } else if (tid < 192) {
        int t = tid - 128;
        float a = bv1[t];
        for (int k = 0; k < HD; ++k) a = fmaf(ro[k], Wv1[(size_t)k * 64 + t], a);
        for (int k = 0; k < SCOMP; ++k) a = fmaf(srow[k], Wv1[(size_t)(HD + k) * 64 + t], a);
        a = fmaxf(a, 0.0f);
        float p = a * Wv2[t];
#pragma unroll
        for (int off = 32; off; off >>= 1) p += __shfl_down(p, off, 64);
        if (tid == 128) vout[m] = p + bv2[0];
    }
    __syncthreads();

    // (c2) fold sC into sAi
    for (int e = tid; e < NPG * HD; e += 256) {
        int i = e >> 7, h = e & 127;
        sAi[i * 132 + h] += sC[h];
    }
    __syncthreads();

    // (d) pair head: fp[i,j,bond]
    if (tid < ASL) {
        int i = tid / 27;
        int j = (tid / 3) % 9;
        int bo = tid % 3;
        float a = bfb[bo];
        const float* pa = sAi + i * 132;
        const float* pb = sBj + j * 132;
        const float* pw = sWfT + bo * HD;
#pragma unroll 8
        for (int h = 0; h < HD; h += 4) {
            const float4 A = *(const float4*)&pa[h];
            const float4 Bv = *(const float4*)&pb[h];
            const float4 W = *(const float4*)&pw[h];
            a = fmaf(fmaxf(A.x + Bv.x, 0.f), W.x, a);
            a = fmaf(fmaxf(A.y + Bv.y, 0.f), W.y, a);
            a = fmaf(fmaxf(A.z + Bv.z, 0.f), W.z, a);
            a = fmaf(fmaxf(A.w + Bv.w, 0.f), W.w, a);
        }
        fp[tid] = a;
    }
    __syncthreads();

    // (e) gather + softmax
    float g = -INFINITY;
    if (tid < ASL) g = fp[indexmask[(size_t)m * ASL + tid]] + mask[(size_t)m * ASL + tid];
    float mx = g;
#pragma unroll
    for (int off = 32; off; off >>= 1) mx = fmaxf(mx, __shfl_down(mx, off, 64));
    if ((tid & 63) == 0) red[tid >> 6] = mx;
    __syncthreads();
    mx = fmaxf(fmaxf(red[0], red[1]), fmaxf(red[2], red[3]));
    float e = (tid < ASL) ? __expf(g - mx) : 0.0f;
    float sm = e;
#pragma unroll
    for (int off = 32; off; off >>= 1) sm += __shfl_down(sm, off, 64);
    if ((tid & 63) == 0) red[4 + (tid >> 6)] = sm;
    __syncthreads();
    sm = red[4] + red[5] + red[6] + red[7];
    if (tid < ASL) out[(size_t)m * ASL + tid] = e / sm;
}

extern "C" void kernel_launch(void* const* d_in, const int* in_sizes, int n_in,
                              void* d_out, int out_size, void* d_ws, size_t ws_size,
                              hipStream_t stream) {
    (void)in_sizes; (void)n_in; (void)out_size; (void)ws_size;
    const float* nf    = (const float*)d_in[0];
    const float* specs = (const float*)d_in[1];
    const float* mask  = (const float*)d_in[3];
    const int*   idxm  = (const int*)d_in[4];
    const float* W1  = (const float*)d_in[5];
    const float* b1  = (const float*)d_in[6];
    const float* W2  = (const float*)d_in[7];
    const float* b2  = (const float*)d_in[8];
    const float* Wv1 = (const float*)d_in[9];
    const float* bv1 = (const float*)d_in[10];
    const float* Wv2 = (const float*)d_in[11];
    const float* bv2 = (const float*)d_in[12];
    const float* Wa2 = (const float*)d_in[13];
    const float* ba2 = (const float*)d_in[14];
    const float* Wf  = (const float*)d_in[15];
    const float* bfv = (const float*)d_in[16];
    float* out = (float*)d_out;
    float* ws  = (float*)d_ws;

    float* sT    = ws;                       // 1856*64  = 118784
    float* s1pre = sT + KT * 64;             // 64*900   = 57600
    float* AB    = s1pre + BATCH * S1DIM;    // 576*256  = 147456

    k_prep<<<dim3(29 + 57), dim3(256), 0, stream>>>(specs, sT, s1pre);
    k_main<<<dim3(NT * KC + N_NODES / 2), dim3(256), 0, stream>>>(sT, W1, nf, Wa2, s1pre, AB);
    k_head<<<dim3(BATCH), dim3(256), 0, stream>>>(s1pre, b1, W2, b2, Wa2, nf,
                                                  Wv1, bv1, Wv2, bv2, ba2, Wf, bfv,
                                                  idxm, mask, AB, out, out + BATCH * ASL);
}

// Round 3
// 137.414 us; speedup vs baseline: 1.2003x; 1.0783x over previous
//
#include <hip/hip_runtime.h>
#include <math.h>

#define BATCH 64
#define NPG 9
#define N_NODES 576
#define HD 128
#define SPEC_LEN 1801
#define S1DIM 900
#define SCOMP 100
#define ASL 243
#define NT 15          // n-tiles of 64 over 900
#define KC 17          // K chunks for GEMM1
#define KCH 106        // 17*106 = 1802 >= 1801
#define KPAD 112       // padded chunk (7*16)
#define KT 1856        // padded sT rows (29*64)

// ---------- Kernel 0: transpose specs -> sT[1856][64] ; zero s1pre+s1c ; AB GEMM ----------
__global__ __launch_bounds__(256) void k_prep(const float* __restrict__ specs,
                                              const float* __restrict__ nf,
                                              const float* __restrict__ Wa2,
                                              float* __restrict__ sT,
                                              float* __restrict__ zbase,
                                              float* __restrict__ AB) {
    int bb = blockIdx.x, tid = threadIdx.x;
    if (bb < 29) {
        __shared__ float t[64 * 65];
        int k0 = bb * 64;
        int kk = tid & 63, mq = tid >> 6;
#pragma unroll
        for (int p = 0; p < 16; ++p) {
            int m = p * 4 + mq;
            int k = k0 + kk;
            float v = (k < SPEC_LEN) ? specs[(size_t)m * SPEC_LEN + k] : 0.0f;
            t[kk * 65 + m] = v;
        }
        __syncthreads();
#pragma unroll
        for (int p = 0; p < 16; ++p) {
            int o = p * 256 + tid;
            sT[(size_t)k0 * 64 + o] = t[(o >> 6) * 65 + (o & 63)];
        }
    } else if (bb < 92) {
        int idx = (bb - 29) * 1024 + tid * 4;
        if (idx < BATCH * S1DIM + BATCH * SCOMP)   // 64000 floats
            *(float4*)(zbase + idx) = make_float4(0.f, 0.f, 0.f, 0.f);
    } else {
        // ---- AB = relu(nf) @ Wa2[0:256], 4 rows/block ----
        __shared__ float snf[4 * HD];
        int ib = (bb - 92) * 4;
        snf[tid]       = fmaxf(nf[(size_t)ib * HD + tid], 0.0f);
        snf[256 + tid] = fmaxf(nf[(size_t)ib * HD + 256 + tid], 0.0f);
        __syncthreads();
        int c = tid;
        const float* __restrict__ wp = (c < HD) ? (Wa2 + c) : (Wa2 + HD * HD + (c - HD));
        float a0 = 0.f, a1 = 0.f, a2 = 0.f, a3 = 0.f;
#pragma unroll 16
        for (int k = 0; k < HD; ++k) {
            float w = wp[(size_t)k * HD];
            a0 = fmaf(snf[k], w, a0);
            a1 = fmaf(snf[HD + k], w, a1);
            a2 = fmaf(snf[2 * HD + k], w, a2);
            a3 = fmaf(snf[3 * HD + k], w, a3);
        }
        AB[(size_t)(ib + 0) * 256 + c] = a0;
        AB[(size_t)(ib + 1) * 256 + c] = a1;
        AB[(size_t)(ib + 2) * 256 + c] = a2;
        AB[(size_t)(ib + 3) * 256 + c] = a3;
    }
}

// ---------- Kernel 1: GEMM1 atomic K-split: s1pre += specs @ W1 (tile 64m x 64n x 106k) ----------
__global__ __launch_bounds__(256) void k_gemm1(const float* __restrict__ sT,
                                               const float* __restrict__ W1,
                                               float* __restrict__ s1pre) {
    __shared__ float w1t[KPAD][64];              // 28672 B
    int bb = blockIdx.x, tid = threadIdx.x;
    int nt = bb % NT, kc = bb / NT;
    int n0 = nt * 64;
    int kb = kc * KCH;
    int klen = min(KCH, SPEC_LEN - kb);          // 106 (105 for last chunk)
    int lane = tid & 63;
    int m0 = __builtin_amdgcn_readfirstlane(tid >> 6) * 16;   // wave-uniform

    // stage whole W1 chunk (zero-padded) — 28 independent coalesced loads/thread
#pragma unroll 7
    for (int e = tid; e < KPAD * 64; e += 256) {
        int kl = e >> 6, nn = e & 63;
        float v = 0.0f;
        if (kl < klen && (n0 + nn) < S1DIM)
            v = W1[(size_t)(kb + kl) * S1DIM + n0 + nn];
        w1t[kl][nn] = v;
    }
    __syncthreads();

    float acc[16];
#pragma unroll
    for (int i = 0; i < 16; ++i) acc[i] = 0.0f;

    const float* __restrict__ sp = sT + (size_t)kb * 64 + m0;  // fully uniform base
#pragma unroll 4
    for (int kk = 0; kk < KPAD; ++kk) {          // fixed trip count; pads are zero
        float w = w1t[kk][lane];
        const float* __restrict__ sa = sp + kk * 64;           // -> s_load
#pragma unroll
        for (int i = 0; i < 16; ++i)
            acc[i] = fmaf(sa[i], w, acc[i]);
    }

    int n = n0 + lane;
    if (n < S1DIM) {
#pragma unroll
        for (int i = 0; i < 16; ++i)
            atomicAdd(&s1pre[(size_t)(m0 + i) * S1DIM + n], acc[i]);
    }
}

// ---------- Kernel 2: GEMM2 atomic K-split: s1c += relu(s1pre+b1) @ W2  (64m x 9kc x 100k) ----------
__global__ __launch_bounds__(128) void k_gemm2(const float* __restrict__ s1pre,
                                               const float* __restrict__ b1,
                                               const float* __restrict__ W2,
                                               float* __restrict__ s1c) {
    __shared__ float sld[SCOMP];
    int bb = blockIdx.x, tid = threadIdx.x;
    int m = bb / 9;
    int kb = (bb % 9) * 100;
    if (tid < 100)
        sld[tid] = fmaxf(s1pre[(size_t)m * S1DIM + kb + tid] + b1[kb + tid], 0.0f);
    __syncthreads();
    if (tid < SCOMP) {
        float a = 0.0f;
#pragma unroll 10
        for (int kl = 0; kl < 100; ++kl)
            a = fmaf(sld[kl], W2[(size_t)(kb + kl) * SCOMP + tid], a);
        atomicAdd(&s1c[(size_t)m * SCOMP + tid], a);
    }
}

// ---------- Kernel 3: per-graph head: D, value, pair features, gather, softmax ----------
__global__ __launch_bounds__(256) void k_head(const float* __restrict__ s1c,
                                              const float* __restrict__ b2,
                                              const float* __restrict__ Wa2,
                                              const float* __restrict__ nf,
                                              const float* __restrict__ Wv1,
                                              const float* __restrict__ bv1,
                                              const float* __restrict__ Wv2,
                                              const float* __restrict__ bv2,
                                              const float* __restrict__ ba2,
                                              const float* __restrict__ Wf,
                                              const float* __restrict__ bfb,
                                              const int* __restrict__ indexmask,
                                              const float* __restrict__ mask,
                                              const float* __restrict__ AB,
                                              float* __restrict__ out,
                                              float* __restrict__ vout) {
    int m = blockIdx.x, tid = threadIdx.x;
    __shared__ __align__(16) float sAi[NPG * 132];
    __shared__ __align__(16) float sBj[NPG * 132];
    __shared__ __align__(16) float sWfT[3 * 132];
    __shared__ __align__(16) float srow[SCOMP];
    __shared__ __align__(16) float ro[HD];
    __shared__ __align__(16) float sC[HD];
    __shared__ float fp[ASL];
    __shared__ float red[8];

    // (a) staging — all independent loads
    for (int e = tid; e < NPG * 256; e += 256) {
        int i = e >> 8, c = e & 255;
        float v = AB[(size_t)(m * NPG + i) * 256 + c];
        if (c < HD) sAi[i * 132 + c] = v;
        else        sBj[i * 132 + (c - HD)] = v;
    }
    for (int e = tid; e < 3 * HD; e += 256)
        sWfT[(e % 3) * 132 + (e / 3)] = Wf[e];
    if (tid < SCOMP)
        srow[tid] = fmaxf(s1c[(size_t)m * SCOMP + tid] + b2[tid], 0.0f);
    if (tid >= 128) {
        int h = tid - 128;
        float a = 0.0f;
#pragma unroll
        for (int i = 0; i < NPG; ++i) a += nf[(size_t)(m * NPG + i) * HD + h];
        ro[h] = a;
    }
    __syncthreads();

    // (b) D + ba2 -> sC (tid<128) | value head (tid 128..191)
    if (tid < HD) {
        float a = 0.0f;
#pragma unroll 10
        for (int k = 0; k < SCOMP; ++k)
            a = fmaf(srow[k], Wa2[(size_t)(2 * HD + k) * HD + tid], a);
        sC[tid] = a + ba2[tid];
    } else if (tid < 192) {
        int t = tid - 128;
        float a = bv1[t];
#pragma unroll 8
        for (int k = 0; k < HD; ++k) a = fmaf(ro[k], Wv1[(size_t)k * 64 + t], a);
#pragma unroll 10
        for (int k = 0; k < SCOMP; ++k) a = fmaf(srow[k], Wv1[(size_t)(HD + k) * 64 + t], a);
        a = fmaxf(a, 0.0f);
        float p = a * Wv2[t];
#pragma unroll
        for (int off = 32; off; off >>= 1) p += __shfl_down(p, off, 64);
        if (tid == 128) vout[m] = p + bv2[0];
    }
    __syncthreads();

    // (c) fold sC into sAi
    for (int e = tid; e < NPG * HD; e += 256)
        sAi[(e >> 7) * 132 + (e & 127)] += sC[e & 127];
    __syncthreads();

    // (d) pair head
    if (tid < ASL) {
        int i = tid / 27;
        int j = (tid / 3) % 9;
        int bo = tid % 3;
        float a = bfb[bo];
        const float* pa = sAi + i * 132;
        const float* pb = sBj + j * 132;
        const float* pw = sWfT + bo * 132;
#pragma unroll 8
        for (int h = 0; h < HD; h += 4) {
            const float4 A = *(const float4*)&pa[h];
            const float4 Bv = *(const float4*)&pb[h];
            const float4 W = *(const float4*)&pw[h];
            a = fmaf(fmaxf(A.x + Bv.x, 0.f), W.x, a);
            a = fmaf(fmaxf(A.y + Bv.y, 0.f), W.y, a);
            a = fmaf(fmaxf(A.z + Bv.z, 0.f), W.z, a);
            a = fmaf(fmaxf(A.w + Bv.w, 0.f), W.w, a);
        }
        fp[tid] = a;
    }
    __syncthreads();

    // (e) gather + softmax
    float g = -INFINITY;
    if (tid < ASL) g = fp[indexmask[(size_t)m * ASL + tid]] + mask[(size_t)m * ASL + tid];
    float mx = g;
#pragma unroll
    for (int off = 32; off; off >>= 1) mx = fmaxf(mx, __shfl_down(mx, off, 64));
    if ((tid & 63) == 0) red[tid >> 6] = mx;
    __syncthreads();
    mx = fmaxf(fmaxf(red[0], red[1]), fmaxf(red[2], red[3]));
    float e = (tid < ASL) ? __expf(g - mx) : 0.0f;
    float sm = e;
#pragma unroll
    for (int off = 32; off; off >>= 1) sm += __shfl_down(sm, off, 64);
    if ((tid & 63) == 0) red[4 + (tid >> 6)] = sm;
    __syncthreads();
    sm = red[4] + red[5] + red[6] + red[7];
    if (tid < ASL) out[(size_t)m * ASL + tid] = e / sm;
}

extern "C" void kernel_launch(void* const* d_in, const int* in_sizes, int n_in,
                              void* d_out, int out_size, void* d_ws, size_t ws_size,
                              hipStream_t stream) {
    (void)in_sizes; (void)n_in; (void)out_size; (void)ws_size;
    const float* nf    = (const float*)d_in[0];
    const float* specs = (const float*)d_in[1];
    const float* mask  = (const float*)d_in[3];
    const int*   idxm  = (const int*)d_in[4];
    const float* W1  = (const float*)d_in[5];
    const float* b1  = (const float*)d_in[6];
    const float* W2  = (const float*)d_in[7];
    const float* b2  = (const float*)d_in[8];
    const float* Wv1 = (const float*)d_in[9];
    const float* bv1 = (const float*)d_in[10];
    const float* Wv2 = (const float*)d_in[11];
    const float* bv2 = (const float*)d_in[12];
    const float* Wa2 = (const float*)d_in[13];
    const float* ba2 = (const float*)d_in[14];
    const float* Wf  = (const float*)d_in[15];
    const float* bfv = (const float*)d_in[16];
    float* out = (float*)d_out;
    float* ws  = (float*)d_ws;

    float* sT    = ws;                       // 1856*64  = 118784
    float* s1pre = sT + KT * 64;             // 64*900   = 57600
    float* s1c   = s1pre + BATCH * S1DIM;    // 64*100   = 6400   (contiguous with s1pre for zeroing)
    float* AB    = s1c + BATCH * SCOMP;      // 576*256  = 147456

    k_prep<<<dim3(92 + 144), dim3(256), 0, stream>>>(specs, nf, Wa2, sT, s1pre, AB);
    k_gemm1<<<dim3(NT * KC), dim3(256), 0, stream>>>(sT, W1, s1pre);
    k_gemm2<<<dim3(BATCH * 9), dim3(128), 0, stream>>>(s1pre, b1, W2, s1c);
    k_head<<<dim3(BATCH), dim3(256), 0, stream>>>(s1c, b2, Wa2, nf,
                                                  Wv1, bv1, Wv2, bv2, ba2, Wf, bfv,
                                                  idxm, mask, AB, out, out + BATCH * ASL);
}